// Round 9
// baseline (163.676 us; speedup 1.0000x reference)
//
#include <hip/hip_runtime.h>
#include <hip/hip_bf16.h>
#include <stdint.h>

// B=2, T=4096, C=512, H=8, D=64. Inputs fp32, output fp32, internals bf16.
// ws (bf16 elems), 32 MiB:
//   Q  [0        .. 4194304)   [B,H,T,D]  (pre-scaled by 0.125*log2e)
//   K  [4194304  .. 8388608)   [B,H,T,D]
//   Vt [8388608  .. 12582912)  [B,H,D,T]
//   Y  [12582912 .. 16777216)  [B,T,C]    (WaT here during QKV; clobbered by attn)
// WpT -> Q region after attn (Q dead). xb (x bf16) in d_out until proj overwrites.

typedef __attribute__((ext_vector_type(8))) short short8;
typedef __attribute__((ext_vector_type(4))) float floatx4;
typedef __attribute__((ext_vector_type(16))) float floatx16;
#if __has_builtin(__builtin_amdgcn_permlane32_swap)
typedef __attribute__((ext_vector_type(2))) unsigned int uint2v;
#define HAVE_PLSWAP 1
#else
#define HAVE_PLSWAP 0
#endif

__device__ __forceinline__ unsigned short f2bf(float f) {
    unsigned int x = __float_as_uint(f);
    unsigned int r = x + 0x7fffu + ((x >> 16) & 1u);
    return (unsigned short)(r >> 16);
}

__device__ __forceinline__ unsigned int pk_bf16(float a, float b) {
    __hip_bfloat162 p = __float22bfloat162_rn(make_float2(a, b));  // v_cvt_pk_bf16_f32
    return *reinterpret_cast<unsigned int*>(&p);
}

// async global->LDS, 16B per lane: per-lane global src, WAVE-UNIFORM lds base,
// HW dest = base + lane*16 (guide m97/m104). Counter: vmcnt (drained by barrier).
__device__ __forceinline__ void gl_lds16(const unsigned short* g, unsigned char* l) {
    __builtin_amdgcn_global_load_lds(
        (const __attribute__((address_space(1))) unsigned int*)g,
        (__attribute__((address_space(3))) unsigned int*)l, 16, 0, 0);
}

// ---------------- P0: fused prep: convert x (blocks 0..2047) + W_attn^T (2048..2815) --
__global__ __launch_bounds__(256) void prep_a(
    const float* __restrict__ x, unsigned short* __restrict__ xb,
    const float* __restrict__ Wa, unsigned short* __restrict__ WaT)
{
    const int bid = blockIdx.x;
    const int tid = threadIdx.x;
    if (bid < 2048) {
        size_t i = ((size_t)bid * 256 + tid) * 8;
        float4 a = *reinterpret_cast<const float4*>(x + i);
        float4 b = *reinterpret_cast<const float4*>(x + i + 4);
        unsigned short o[8] = {f2bf(a.x), f2bf(a.y), f2bf(a.z), f2bf(a.w),
                               f2bf(b.x), f2bf(b.y), f2bf(b.z), f2bf(b.w)};
        *reinterpret_cast<uint4*>(xb + i) = *reinterpret_cast<uint4*>(o);
    } else {
        __shared__ unsigned short tile[32][34];
        const int t2 = bid - 2048;           // 48 n-tiles x 16 k-tiles
        const int n0 = (t2 % 48) * 32, k0 = (t2 / 48) * 32;
        const int tx = tid & 31, ty = tid >> 5;
        #pragma unroll
        for (int p = 0; p < 4; ++p)
            tile[tx][ty + p * 8] = f2bf(Wa[(size_t)(k0 + ty + p * 8) * 1536 + n0 + tx]);
        __syncthreads();
        #pragma unroll
        for (int p = 0; p < 4; ++p)
            WaT[(size_t)(n0 + ty + p * 8) * 512 + k0 + tx] = tile[ty + p * 8][tx];
    }
}

// ---------------- P1: W_proj [512][512] fp32 -> WpT [512][512] bf16 -------------------
__global__ __launch_bounds__(256) void transpose_wp(
    const float* __restrict__ W, unsigned short* __restrict__ Wt)
{
    __shared__ unsigned short tile[32][34];
    const int tid = threadIdx.x;
    const int tx = tid & 31, ty = tid >> 5;
    const int n0 = blockIdx.x * 32, k0 = blockIdx.y * 32;
    #pragma unroll
    for (int p = 0; p < 4; ++p)
        tile[tx][ty + p * 8] = f2bf(W[(size_t)(k0 + ty + p * 8) * 512 + n0 + tx]);
    __syncthreads();
    #pragma unroll
    for (int p = 0; p < 4; ++p)
        Wt[(size_t)(n0 + ty + p * 8) * 512 + k0 + tx] = tile[ty + p * 8][tx];
}

// ---------------- MFMA GEMM, m97-structure: 128x128, BK=32, global_load_lds dbuf ------
// Staging is now async DMA (guide m93->m97: 517->874 TF measured on this structure):
// linear LDS tiles [128][32] bf16, buffers A0@0 B0@8192 A1@16384 B1@24576 (32 KB);
// per iter each wave issues 4 gl_lds16 (A/B x 2 row-groups); the __syncthreads() at
// the top of the next iter drains vmcnt -> prefetch completes under the MFMA phase.
// Frag ds_read_b128 at 64B row stride = 2-way/phase = free (m136). VGPR drops (no
// staging regs) -> 4 blocks/CU resident. EPI epilogues unchanged (Tr overlays smem).
template<int EPI>
__global__ __launch_bounds__(256) void mm_bt(
    const unsigned short* __restrict__ A,
    const unsigned short* __restrict__ Bt,
    void* __restrict__ outp)
{
    __shared__ __align__(16) unsigned char smem[40960];

    const int tid  = threadIdx.x;
    const int wave = tid >> 6;
    const int lane = tid & 63;
    const int quad = lane >> 4;
    const int l16  = lane & 15;
    const int wr   = wave >> 1;
    const int wc   = wave & 1;
    const int m0 = blockIdx.x * 128;
    const int n0 = blockIdx.y * 128;

    floatx4 acc[4][4];
    #pragma unroll
    for (int i = 0; i < 4; ++i)
        #pragma unroll
        for (int j = 0; j < 4; ++j) acc[i][j] = (floatx4){0.f, 0.f, 0.f, 0.f};

    // DMA source lanes: lds slot s = (call*4+wave)*64 + lane; row = s>>2, chunk = s&3.
    // => call 0 rows wave*16+(lane>>2), call 1 rows +64; chunk = lane&3 (8 shorts).
    const unsigned short* aS = A  + (size_t)(m0 + wave * 16 + (lane >> 2)) * 512 + (lane & 3) * 8;
    const unsigned short* bS = Bt + (size_t)(n0 + wave * 16 + (lane >> 2)) * 512 + (lane & 3) * 8;

#define STAGE(K0S, BUF)                                                     \
    {   unsigned char* Ab = smem + (BUF) * 16384 + wave * 1024;             \
        gl_lds16(aS + (K0S),             Ab);                               \
        gl_lds16(aS + (K0S) + 64 * 512,  Ab + 4096);                        \
        gl_lds16(bS + (K0S),             Ab + 8192);                        \
        gl_lds16(bS + (K0S) + 64 * 512,  Ab + 12288);                       \
    }

    STAGE(0, 0);

    for (int it = 0; it < 16; ++it) {
        __syncthreads();                     // drains vmcnt: buf[it&1] fully staged
        if (it < 15) STAGE((it + 1) * 32, (it & 1) ^ 1);

        const unsigned char* Al = smem + (it & 1) * 16384;
        const unsigned char* Bl = Al + 8192;

        short8 af[4], bf[4];
        #pragma unroll
        for (int ti = 0; ti < 4; ++ti)
            af[ti] = *reinterpret_cast<const short8*>(
                Al + (wr * 64 + ti * 16 + l16) * 64 + quad * 16);
        #pragma unroll
        for (int tj = 0; tj < 4; ++tj)
            bf[tj] = *reinterpret_cast<const short8*>(
                Bl + (wc * 64 + tj * 16 + l16) * 64 + quad * 16);
        #pragma unroll
        for (int ti = 0; ti < 4; ++ti)
            #pragma unroll
            for (int tj = 0; tj < 4; ++tj)
                acc[ti][tj] = __builtin_amdgcn_mfma_f32_16x16x32_bf16(af[ti], bf[tj], acc[ti][tj], 0, 0, 0);
    }
#undef STAGE

    if (EPI == 0) {
        unsigned short* WS = (unsigned short*)outp;
        unsigned short* Qb  = WS;
        unsigned short* Kb  = WS + 4194304;
        unsigned short* Vtb = WS + 8388608;
        const int which = n0 >> 9;
        const int h = ((n0 + wc * 64) >> 6) & 7;

        if (which == 2) {
            auto Tr = reinterpret_cast<unsigned short(*)[80]>(smem);   // [256][80]
            __syncthreads();
            #pragma unroll
            for (int ti = 0; ti < 4; ++ti)
                #pragma unroll
                for (int tj = 0; tj < 4; ++tj) {
                    unsigned int lo = pk_bf16(acc[ti][tj][0], acc[ti][tj][1]);
                    unsigned int hi = pk_bf16(acc[ti][tj][2], acc[ti][tj][3]);
                    *reinterpret_cast<uint2*>(&Tr[(wave << 6) + tj * 16 + l16][ti * 16 + quad * 4])
                        = make_uint2(lo, hi);
                }
            const int b = m0 >> 12;
            const int bh = b * 8 + h;
            const int t0g = (m0 & 4095) + wr * 64;
            const int tseg = (lane & 7) * 8;
            #pragma unroll
            for (int p = 0; p < 8; ++p) {
                int dl = p * 8 + (lane >> 3);
                uint4 v = *reinterpret_cast<const uint4*>(&Tr[(wave << 6) + dl][tseg]);
                *reinterpret_cast<uint4*>(&Vtb[((size_t)(bh * 64 + dl)) * 4096 + t0g + tseg]) = v;
            }
        } else {
            const float sc = (which == 0) ? 0.18033688f : 1.0f;  // 0.125*log2(e)
            #pragma unroll
            for (int ti = 0; ti < 4; ++ti) {
                #pragma unroll
                for (int r = 0; r < 4; ++r) {
                    int m = m0 + wr * 64 + ti * 16 + quad * 4 + r;
                    int b = m >> 12, t = m & 4095;
                    int bh = b * 8 + h;
                    #pragma unroll
                    for (int tj = 0; tj < 4; ++tj) {
                        int d = tj * 16 + l16;
                        unsigned short val = f2bf(acc[ti][tj][r] * sc);
                        if (which == 0) Qb[((size_t)bh * 4096 + t) * 64 + d] = val;
                        else            Kb[((size_t)bh * 4096 + t) * 64 + d] = val;
                    }
                }
            }
        }
    } else {
        float* Out = (float*)outp;
        #pragma unroll
        for (int ti = 0; ti < 4; ++ti) {
            #pragma unroll
            for (int r = 0; r < 4; ++r) {
                int m = m0 + wr * 64 + ti * 16 + quad * 4 + r;
                #pragma unroll
                for (int tj = 0; tj < 4; ++tj) {
                    int n = n0 + wc * 64 + tj * 16 + l16;
                    Out[(size_t)m * 512 + n] = acc[ti][tj][r];
                }
            }
        }
    }
}

// ---------------- MFMA flash attention: r8 VERBATIM (best: 61.6 us) -------------------
// Block = 64 q-rows, 256 threads, 1024 blocks (64 qb x 16 bh), balanced permutation,
// 4 blocks/CU resident (LDS 32 KB). Wave (p = wave>>1, w = wave&1): q-rows m0+32p..+31
// vs key half 32w..32w+31. Rowsum via ones-MFMA; incremental prefetch pointers.
__global__ __launch_bounds__(256) void attn_mfma(
    const unsigned short* __restrict__ Q,
    const unsigned short* __restrict__ K,
    const unsigned short* __restrict__ Vt,
    unsigned short* __restrict__ Y)
{
    __shared__ __align__(16) unsigned short Kc[2][64][64];
    __shared__ __align__(16) unsigned short Vc[2][64][64];

    const int tid  = threadIdx.x;
    const int wave = tid >> 6;
    const int lane = tid & 63;
    const int l32  = lane & 31;
    const int hh   = lane >> 5;
    const int swz  = l32 & 7;
    const int p    = wave >> 1;      // q-half of block (rows m0+32p .. +31)
    const int w    = wave & 1;       // key-half of tile (keys 32w .. 32w+31)

    // balanced qb permutation (r3/r5-proven): per-CU tile count = const 130
    const int bid = blockIdx.x;
    const int bh  = bid & 15;
    const int j   = (bid >> 4) & 15;
    const int g   = bid >> 8;
    const int qb  = (g == 0) ? j : (g == 1) ? (63 - j) : (g == 2) ? (16 + j) : (47 - j);
    const int m0  = qb * 64;

    const unsigned short* Qp = Q  + (size_t)bh * (4096 * 64);
    const unsigned short* Kp = K  + (size_t)bh * (4096 * 64);
    const unsigned short* Vp = Vt + (size_t)bh * (64 * 4096);

    // Q B-frags (pre-scaled upstream): col q = m0+32p+l32, k(d) = k16*16 + hh*8 + jj
    short8 qf[4];
    #pragma unroll
    for (int k16 = 0; k16 < 4; ++k16)
        qf[k16] = *reinterpret_cast<const short8*>(
            &Qp[(size_t)(m0 + 32 * p + l32) * 64 + k16 * 16 + hh * 8]);

    short8 ones;
    #pragma unroll
    for (int i = 0; i < 8; ++i) ones[i] = (short)0x3F80;

    floatx16 o0 = {0,0,0,0,0,0,0,0,0,0,0,0,0,0,0,0};   // O[q][d=l32]
    floatx16 o1 = {0,0,0,0,0,0,0,0,0,0,0,0,0,0,0,0};   // O[q][d=32+l32]
    floatx16 o4 = {0,0,0,0,0,0,0,0,0,0,0,0,0,0,0,0};   // rowsum (ones-MFMA)

    // staging: thread covers rows rr, rr+32 at 16B chunk cc; XOR-swizzled (r1-proven)
    const int rr  = tid >> 3;
    const int cc  = tid & 7;
    const int c0  = cc * 8;
    const int scs = ((cc ^ (rr & 7)) << 3);

    uint4 rk0 = *reinterpret_cast<const uint4*>(&Kp[(size_t)rr * 64 + c0]);
    uint4 rk1 = *reinterpret_cast<const uint4*>(&Kp[(size_t)(rr + 32) * 64 + c0]);
    uint4 rv0 = *reinterpret_cast<const uint4*>(&Vp[(size_t)rr * 4096 + c0]);
    uint4 rv1 = *reinterpret_cast<const uint4*>(&Vp[(size_t)(rr + 32) * 4096 + c0]);
    *reinterpret_cast<uint4*>(&Kc[0][rr][scs])      = rk0;
    *reinterpret_cast<uint4*>(&Kc[0][rr + 32][scs]) = rk1;
    *reinterpret_cast<uint4*>(&Vc[0][rr][scs])      = rv0;
    *reinterpret_cast<uint4*>(&Vc[0][rr + 32][scs]) = rv1;

    // incremental prefetch pointers (tile 1 positions)
    const unsigned short* kq0 = Kp + (size_t)(64 + rr) * 64 + c0;
    const unsigned short* kq1 = Kp + (size_t)(64 + rr + 32) * 64 + c0;
    const unsigned short* vq0 = Vp + (size_t)rr * 4096 + 64 + c0;
    const unsigned short* vq1 = Vp + (size_t)(rr + 32) * 4096 + 64 + c0;

    const int NT = qb + 1;
    for (int kt = 0; kt < NT; ++kt) {
        __syncthreads();
        const int cur = kt & 1;
        const int nxt = cur ^ 1;

        if (kt + 1 < NT) {   // prefetch next tile into registers
            rk0 = *reinterpret_cast<const uint4*>(kq0);
            rk1 = *reinterpret_cast<const uint4*>(kq1);
            rv0 = *reinterpret_cast<const uint4*>(vq0);
            rv1 = *reinterpret_cast<const uint4*>(vq1);
            kq0 += 4096; kq1 += 4096; vq0 += 64; vq1 += 64;
        }

        // only fully-masked case: q-half 0's key-half 1 on the diagonal tile
        const bool active = (kt < qb) || (w == 0) || (p == 1);
        if (active) {
            // ---- QK^T: S[key][q], A = K rows 32w+l32, B = Q ----
            floatx16 s = {0,0,0,0,0,0,0,0,0,0,0,0,0,0,0,0};
            #pragma unroll
            for (int k16 = 0; k16 < 4; ++k16) {
                const int chs = ((2 * k16 + hh) ^ swz) << 3;
                short8 a = *reinterpret_cast<const short8*>(&Kc[cur][32 * w + l32][chs]);
                s = __builtin_amdgcn_mfma_f32_32x32x16_bf16(a, qf[k16], s, 0, 0, 0);
            }
            if (kt == qb) {   // diagonal: key_local = 32w + (r&3)+8*(r>>2)+4*hh
                const int ql = 32 * p + l32;
                #pragma unroll
                for (int r = 0; r < 16; ++r) {
                    const int kl = 32 * w + (r & 3) + 8 * (r >> 2) + 4 * hh;
                    s[r] = (kl <= ql) ? s[r] : -1e30f;
                }
            }
            #pragma unroll
            for (int r = 0; r < 16; ++r) s[r] = __builtin_amdgcn_exp2f(s[r]);

            // ---- P -> PV A-frags in registers (r4/r5-verified construction) ----
            unsigned int A0 = pk_bf16(s[0],  s[1]),  B0 = pk_bf16(s[2],  s[3]);
            unsigned int A1 = pk_bf16(s[4],  s[5]),  B1 = pk_bf16(s[6],  s[7]);
            unsigned int A2 = pk_bf16(s[8],  s[9]),  B2 = pk_bf16(s[10], s[11]);
            unsigned int A3 = pk_bf16(s[12], s[13]), B3 = pk_bf16(s[14], s[15]);
            short8 pa[2];
#if HAVE_PLSWAP
            {
                uint2v rA = __builtin_amdgcn_permlane32_swap(A0, A1, false, false);
                uint2v rB = __builtin_amdgcn_permlane32_swap(B0, B1, false, false);
                uint4 u0 = make_uint4(rA[0], rB[0], rA[1], rB[1]);
                pa[0] = *reinterpret_cast<short8*>(&u0);
                rA = __builtin_amdgcn_permlane32_swap(A2, A3, false, false);
                rB = __builtin_amdgcn_permlane32_swap(B2, B3, false, false);
                uint4 u1 = make_uint4(rA[0], rB[0], rA[1], rB[1]);
                pa[1] = *reinterpret_cast<short8*>(&u1);
            }
#else
            {
                unsigned int pA0 = __shfl_xor((int)A0, 32), pA1 = __shfl_xor((int)A1, 32);
                unsigned int pB0 = __shfl_xor((int)B0, 32), pB1 = __shfl_xor((int)B1, 32);
                unsigned int pA2 = __shfl_xor((int)A2, 32), pA3 = __shfl_xor((int)A3, 32);
                unsigned int pB2 = __shfl_xor((int)B2, 32), pB3 = __shfl_xor((int)B3, 32);
                uint4 u0 = make_uint4(hh ? pA1 : A0, hh ? pB1 : B0,
                                      hh ? A1 : pA0, hh ? B1 : pB0);
                pa[0] = *reinterpret_cast<short8*>(&u0);
                uint4 u1 = make_uint4(hh ? pA3 : A2, hh ? pB3 : B2,
                                      hh ? A3 : pA2, hh ? B3 : pB2);
                pa[1] = *reinterpret_cast<short8*>(&u1);
            }
#endif
            // rowsum on the MFMA pipe (same bf16 P values PV consumes; r7-verified)
            o4 = __builtin_amdgcn_mfma_f32_32x32x16_bf16(pa[0], ones, o4, 0, 0, 0);
            o4 = __builtin_amdgcn_mfma_f32_32x32x16_bf16(pa[1], ones, o4, 0, 0, 0);

            // ---- PV: O[q][d] over key window 32w..32w+31; B = V[key][d] ----
            #pragma unroll
            for (int f = 0; f < 2; ++f) {
                const int chs = ((4 * w + 2 * f + hh) ^ swz) << 3;
                short8 b0 = *reinterpret_cast<const short8*>(&Vc[cur][l32][chs]);
                short8 b1 = *reinterpret_cast<const short8*>(&Vc[cur][32 + l32][chs]);
                o0 = __builtin_amdgcn_mfma_f32_32x32x16_bf16(pa[f], b0, o0, 0, 0, 0);
                o1 = __builtin_amdgcn_mfma_f32_32x32x16_bf16(pa[f], b1, o1, 0, 0, 0);
            }
        }

        if (kt + 1 < NT) {   // stage prefetched tile into the idle buffer
            *reinterpret_cast<uint4*>(&Kc[nxt][rr][scs])      = rk0;
            *reinterpret_cast<uint4*>(&Kc[nxt][rr + 32][scs]) = rk1;
            *reinterpret_cast<uint4*>(&Vc[nxt][rr][scs])      = rv0;
            *reinterpret_cast<uint4*>(&Vc[nxt][rr + 32][scs]) = rv1;
        }
    }

    // ---- epilogue (r7-verified): combine across wave pair via LDS ----
    __syncthreads();                                       // all tile reads done
    float* Ob  = reinterpret_cast<float*>(&Kc[0][0][0]);   // [4][32][32] f32 = 16 KB
    float* Wsf = reinterpret_cast<float*>(&Vc[0][0][0]);   // [4][32] rowsums by q
    if (l32 == 0) {
        #pragma unroll
        for (int r = 0; r < 16; ++r) {
            const int qloc = (r & 3) + 8 * (r >> 2) + 4 * hh;
            Wsf[(p * 2 + w) * 32 + qloc] = o4[r];          // o4 duplicated over cols
        }
    }
    #pragma unroll
    for (int r = 0; r < 16; ++r) {                         // give away partner half
        const int qloc = (r & 3) + 8 * (r >> 2) + 4 * hh;
        Ob[((p * 2 + w) * 32 + qloc) * 32 + l32] = w ? o0[r] : o1[r];
    }
    __syncthreads();

    const int b = bh >> 3, h = bh & 7;
    #pragma unroll
    for (int gg = 0; gg < 4; ++gg) {
        float4 a4 = *reinterpret_cast<const float4*>(&Wsf[(p * 2 + 0) * 32 + 8 * gg + 4 * hh]);
        float4 b4 = *reinterpret_cast<const float4*>(&Wsf[(p * 2 + 1) * 32 + 8 * gg + 4 * hh]);
        const float ra[4] = {a4.x + b4.x, a4.y + b4.y, a4.z + b4.z, a4.w + b4.w};
        #pragma unroll
        for (int rsub = 0; rsub < 4; ++rsub) {
            const int r = gg * 4 + rsub;
            const int qloc = 8 * gg + 4 * hh + rsub;
            const float cmb = (w ? o1[r] : o0[r])
                            + Ob[((p * 2 + (1 - w)) * 32 + qloc) * 32 + l32];
            const int t = m0 + 32 * p + qloc;
            Y[((size_t)(b * 4096 + t)) * 512 + h * 64 + 32 * w + l32]
                = f2bf(cmb / ra[rsub]);
        }
    }
}

extern "C" void kernel_launch(void* const* d_in, const int* in_sizes, int n_in,
                              void* d_out, int out_size, void* d_ws, size_t ws_size,
                              hipStream_t stream) {
    const float* x  = (const float*)d_in[0];
    const float* Wa = (const float*)d_in[1];
    const float* Wp = (const float*)d_in[2];
    float* out = (float*)d_out;
    unsigned short* ws = (unsigned short*)d_ws;

    unsigned short* Qb  = ws;
    unsigned short* Kb  = ws + 4194304;
    unsigned short* Vtb = ws + 8388608;
    unsigned short* Yb  = ws + 12582912;
    unsigned short* WaT = Yb;                      // W_attn^T during QKV only
    unsigned short* WpT = Qb;                      // W_proj^T after attn (Q dead)
    unsigned short* xb  = (unsigned short*)d_out;  // x bf16; overwritten by proj

    prep_a<<<dim3(2816), dim3(256), 0, stream>>>(x, xb, Wa, WaT);
    mm_bt<0><<<dim3(64, 12), dim3(256), 0, stream>>>(xb, WaT, (void*)ws);
    attn_mfma<<<dim3(1024), dim3(256), 0, stream>>>(Qb, Kb, Vtb, Yb);
    transpose_wp<<<dim3(16, 16), dim3(256), 0, stream>>>(Wp, WpT);
    mm_bt<1><<<dim3(64, 4), dim3(256), 0, stream>>>(Yb, WpT, (void*)out);
}

// Round 10
// 157.804 us; speedup vs baseline: 1.0372x; 1.0372x over previous
//
#include <hip/hip_runtime.h>
#include <hip/hip_bf16.h>
#include <stdint.h>

// B=2, T=4096, C=512, H=8, D=64. Inputs fp32, output fp32, internals bf16.
// ws (bf16 elems), 32 MiB:
//   Q  [0        .. 4194304)   [B,H,T,D]  (pre-scaled by 0.125*log2e)
//   K  [4194304  .. 8388608)   [B,H,T,D]
//   Vt [8388608  .. 12582912)  [B,H,D,T]
//   Y  [12582912 .. 16777216)  [B,T,C]    (WaT here during QKV; clobbered by attn)
// WpT -> Q region after attn (Q dead). xb (x bf16) in d_out until proj overwrites.

typedef __attribute__((ext_vector_type(8))) short short8;
typedef __attribute__((ext_vector_type(4))) float floatx4;
typedef __attribute__((ext_vector_type(16))) float floatx16;
#if __has_builtin(__builtin_amdgcn_permlane32_swap)
typedef __attribute__((ext_vector_type(2))) unsigned int uint2v;
#define HAVE_PLSWAP 1
#else
#define HAVE_PLSWAP 0
#endif

__device__ __forceinline__ unsigned short f2bf(float f) {
    unsigned int x = __float_as_uint(f);
    unsigned int r = x + 0x7fffu + ((x >> 16) & 1u);
    return (unsigned short)(r >> 16);
}

__device__ __forceinline__ unsigned int pk_bf16(float a, float b) {
    __hip_bfloat162 p = __float22bfloat162_rn(make_float2(a, b));  // v_cvt_pk_bf16_f32
    return *reinterpret_cast<unsigned int*>(&p);
}

// async global->LDS, 16B per lane (mm_bt staging; guide m97)
__device__ __forceinline__ void gl_lds16(const unsigned short* g, unsigned char* l) {
    __builtin_amdgcn_global_load_lds(
        (const __attribute__((address_space(1))) unsigned int*)g,
        (__attribute__((address_space(3))) unsigned int*)l, 16, 0, 0);
}

// ---- one K-tile step for one wave (r5/r8-verified core): rows 32*p2.., keys 32*w.. --
__device__ __forceinline__ void attn_tile(
    const unsigned short* __restrict__ Kbuf,   // [64][64] swizzled
    const unsigned short* __restrict__ Vbuf,   // [64][64] swizzled
    const short8* qf, const short8& ones, bool dg,
    int l32, int hh, int swz, int w, int p2,
    floatx16& o0, floatx16& o1, floatx16& o4)
{
    floatx16 s = {0,0,0,0,0,0,0,0,0,0,0,0,0,0,0,0};
    #pragma unroll
    for (int k16 = 0; k16 < 4; ++k16) {
        const int chs = ((2 * k16 + hh) ^ swz) << 3;
        short8 a = *reinterpret_cast<const short8*>(&Kbuf[(32 * w + l32) * 64 + chs]);
        s = __builtin_amdgcn_mfma_f32_32x32x16_bf16(a, qf[k16], s, 0, 0, 0);
    }
    if (dg) {   // diagonal: key_local = 32w + (r&3)+8*(r>>2)+4*hh ; q_local = 32p2+l32
        const int ql = 32 * p2 + l32;
        #pragma unroll
        for (int r = 0; r < 16; ++r) {
            const int kl = 32 * w + (r & 3) + 8 * (r >> 2) + 4 * hh;
            s[r] = (kl <= ql) ? s[r] : -1e30f;
        }
    }
    #pragma unroll
    for (int r = 0; r < 16; ++r) s[r] = __builtin_amdgcn_exp2f(s[r]);

    unsigned int A0 = pk_bf16(s[0],  s[1]),  B0 = pk_bf16(s[2],  s[3]);
    unsigned int A1 = pk_bf16(s[4],  s[5]),  B1 = pk_bf16(s[6],  s[7]);
    unsigned int A2 = pk_bf16(s[8],  s[9]),  B2 = pk_bf16(s[10], s[11]);
    unsigned int A3 = pk_bf16(s[12], s[13]), B3 = pk_bf16(s[14], s[15]);
    short8 pa[2];
#if HAVE_PLSWAP
    {
        uint2v rA = __builtin_amdgcn_permlane32_swap(A0, A1, false, false);
        uint2v rB = __builtin_amdgcn_permlane32_swap(B0, B1, false, false);
        uint4 u0 = make_uint4(rA[0], rB[0], rA[1], rB[1]);
        pa[0] = *reinterpret_cast<short8*>(&u0);
        rA = __builtin_amdgcn_permlane32_swap(A2, A3, false, false);
        rB = __builtin_amdgcn_permlane32_swap(B2, B3, false, false);
        uint4 u1 = make_uint4(rA[0], rB[0], rA[1], rB[1]);
        pa[1] = *reinterpret_cast<short8*>(&u1);
    }
#else
    {
        unsigned int pA0 = __shfl_xor((int)A0, 32), pA1 = __shfl_xor((int)A1, 32);
        unsigned int pB0 = __shfl_xor((int)B0, 32), pB1 = __shfl_xor((int)B1, 32);
        unsigned int pA2 = __shfl_xor((int)A2, 32), pA3 = __shfl_xor((int)A3, 32);
        unsigned int pB2 = __shfl_xor((int)B2, 32), pB3 = __shfl_xor((int)B3, 32);
        uint4 u0 = make_uint4(hh ? pA1 : A0, hh ? pB1 : B0,
                              hh ? A1 : pA0, hh ? B1 : pB0);
        pa[0] = *reinterpret_cast<short8*>(&u0);
        uint4 u1 = make_uint4(hh ? pA3 : A2, hh ? pB3 : B2,
                              hh ? A3 : pA2, hh ? B3 : pB2);
        pa[1] = *reinterpret_cast<short8*>(&u1);
    }
#endif
    o4 = __builtin_amdgcn_mfma_f32_32x32x16_bf16(pa[0], ones, o4, 0, 0, 0);
    o4 = __builtin_amdgcn_mfma_f32_32x32x16_bf16(pa[1], ones, o4, 0, 0, 0);
    #pragma unroll
    for (int f = 0; f < 2; ++f) {
        const int chs = ((4 * w + 2 * f + hh) ^ swz) << 3;
        short8 b0 = *reinterpret_cast<const short8*>(&Vbuf[l32 * 64 + chs]);
        short8 b1 = *reinterpret_cast<const short8*>(&Vbuf[(32 + l32) * 64 + chs]);
        o0 = __builtin_amdgcn_mfma_f32_32x32x16_bf16(pa[f], b0, o0, 0, 0, 0);
        o1 = __builtin_amdgcn_mfma_f32_32x32x16_bf16(pa[f], b1, o1, 0, 0, 0);
    }
}

// ---------------- P0: fused prep: convert x (blocks 0..2047) + W_attn^T (2048..2815) --
__global__ __launch_bounds__(256) void prep_a(
    const float* __restrict__ x, unsigned short* __restrict__ xb,
    const float* __restrict__ Wa, unsigned short* __restrict__ WaT)
{
    const int bid = blockIdx.x;
    const int tid = threadIdx.x;
    if (bid < 2048) {
        size_t i = ((size_t)bid * 256 + tid) * 8;
        float4 a = *reinterpret_cast<const float4*>(x + i);
        float4 b = *reinterpret_cast<const float4*>(x + i + 4);
        unsigned short o[8] = {f2bf(a.x), f2bf(a.y), f2bf(a.z), f2bf(a.w),
                               f2bf(b.x), f2bf(b.y), f2bf(b.z), f2bf(b.w)};
        *reinterpret_cast<uint4*>(xb + i) = *reinterpret_cast<uint4*>(o);
    } else {
        __shared__ unsigned short tile[32][34];
        const int t2 = bid - 2048;           // 48 n-tiles x 16 k-tiles
        const int n0 = (t2 % 48) * 32, k0 = (t2 / 48) * 32;
        const int tx = tid & 31, ty = tid >> 5;
        #pragma unroll
        for (int p = 0; p < 4; ++p)
            tile[tx][ty + p * 8] = f2bf(Wa[(size_t)(k0 + ty + p * 8) * 1536 + n0 + tx]);
        __syncthreads();
        #pragma unroll
        for (int p = 0; p < 4; ++p)
            WaT[(size_t)(n0 + ty + p * 8) * 512 + k0 + tx] = tile[ty + p * 8][tx];
    }
}

// ---------------- P1: W_proj [512][512] fp32 -> WpT [512][512] bf16 -------------------
__global__ __launch_bounds__(256) void transpose_wp(
    const float* __restrict__ W, unsigned short* __restrict__ Wt)
{
    __shared__ unsigned short tile[32][34];
    const int tid = threadIdx.x;
    const int tx = tid & 31, ty = tid >> 5;
    const int n0 = blockIdx.x * 32, k0 = blockIdx.y * 32;
    #pragma unroll
    for (int p = 0; p < 4; ++p)
        tile[tx][ty + p * 8] = f2bf(W[(size_t)(k0 + ty + p * 8) * 512 + n0 + tx]);
    __syncthreads();
    #pragma unroll
    for (int p = 0; p < 4; ++p)
        Wt[(size_t)(n0 + ty + p * 8) * 512 + k0 + tx] = tile[ty + p * 8][tx];
}

// ---------------- MFMA GEMM, m97-structure: 128x128, BK=32, global_load_lds dbuf ------
template<int EPI>
__global__ __launch_bounds__(256) void mm_bt(
    const unsigned short* __restrict__ A,
    const unsigned short* __restrict__ Bt,
    void* __restrict__ outp)
{
    __shared__ __align__(16) unsigned char smem[40960];

    const int tid  = threadIdx.x;
    const int wave = tid >> 6;
    const int lane = tid & 63;
    const int quad = lane >> 4;
    const int l16  = lane & 15;
    const int wr   = wave >> 1;
    const int wc   = wave & 1;
    const int m0 = blockIdx.x * 128;
    const int n0 = blockIdx.y * 128;

    floatx4 acc[4][4];
    #pragma unroll
    for (int i = 0; i < 4; ++i)
        #pragma unroll
        for (int j = 0; j < 4; ++j) acc[i][j] = (floatx4){0.f, 0.f, 0.f, 0.f};

    const unsigned short* aS = A  + (size_t)(m0 + wave * 16 + (lane >> 2)) * 512 + (lane & 3) * 8;
    const unsigned short* bS = Bt + (size_t)(n0 + wave * 16 + (lane >> 2)) * 512 + (lane & 3) * 8;

#define STAGE(K0S, BUF)                                                     \
    {   unsigned char* Ab = smem + (BUF) * 16384 + wave * 1024;             \
        gl_lds16(aS + (K0S),             Ab);                               \
        gl_lds16(aS + (K0S) + 64 * 512,  Ab + 4096);                        \
        gl_lds16(bS + (K0S),             Ab + 8192);                        \
        gl_lds16(bS + (K0S) + 64 * 512,  Ab + 12288);                       \
    }

    STAGE(0, 0);

    for (int it = 0; it < 16; ++it) {
        __syncthreads();                     // drains vmcnt: buf[it&1] fully staged
        if (it < 15) STAGE((it + 1) * 32, (it & 1) ^ 1);

        const unsigned char* Al = smem + (it & 1) * 16384;
        const unsigned char* Bl = Al + 8192;

        short8 af[4], bf[4];
        #pragma unroll
        for (int ti = 0; ti < 4; ++ti)
            af[ti] = *reinterpret_cast<const short8*>(
                Al + (wr * 64 + ti * 16 + l16) * 64 + quad * 16);
        #pragma unroll
        for (int tj = 0; tj < 4; ++tj)
            bf[tj] = *reinterpret_cast<const short8*>(
                Bl + (wc * 64 + tj * 16 + l16) * 64 + quad * 16);
        #pragma unroll
        for (int ti = 0; ti < 4; ++ti)
            #pragma unroll
            for (int tj = 0; tj < 4; ++tj)
                acc[ti][tj] = __builtin_amdgcn_mfma_f32_16x16x32_bf16(af[ti], bf[tj], acc[ti][tj], 0, 0, 0);
    }
#undef STAGE

    if (EPI == 0) {
        unsigned short* WS = (unsigned short*)outp;
        unsigned short* Qb  = WS;
        unsigned short* Kb  = WS + 4194304;
        unsigned short* Vtb = WS + 8388608;
        const int which = n0 >> 9;
        const int h = ((n0 + wc * 64) >> 6) & 7;

        if (which == 2) {
            auto Tr = reinterpret_cast<unsigned short(*)[80]>(smem);   // [256][80]
            __syncthreads();
            #pragma unroll
            for (int ti = 0; ti < 4; ++ti)
                #pragma unroll
                for (int tj = 0; tj < 4; ++tj) {
                    unsigned int lo = pk_bf16(acc[ti][tj][0], acc[ti][tj][1]);
                    unsigned int hi = pk_bf16(acc[ti][tj][2], acc[ti][tj][3]);
                    *reinterpret_cast<uint2*>(&Tr[(wave << 6) + tj * 16 + l16][ti * 16 + quad * 4])
                        = make_uint2(lo, hi);
                }
            const int b = m0 >> 12;
            const int bh = b * 8 + h;
            const int t0g = (m0 & 4095) + wr * 64;
            const int tseg = (lane & 7) * 8;
            #pragma unroll
            for (int p = 0; p < 8; ++p) {
                int dl = p * 8 + (lane >> 3);
                uint4 v = *reinterpret_cast<const uint4*>(&Tr[(wave << 6) + dl][tseg]);
                *reinterpret_cast<uint4*>(&Vtb[((size_t)(bh * 64 + dl)) * 4096 + t0g + tseg]) = v;
            }
        } else {
            const float sc = (which == 0) ? 0.18033688f : 1.0f;  // 0.125*log2(e)
            #pragma unroll
            for (int ti = 0; ti < 4; ++ti) {
                #pragma unroll
                for (int r = 0; r < 4; ++r) {
                    int m = m0 + wr * 64 + ti * 16 + quad * 4 + r;
                    int b = m >> 12, t = m & 4095;
                    int bh = b * 8 + h;
                    #pragma unroll
                    for (int tj = 0; tj < 4; ++tj) {
                        int d = tj * 16 + l16;
                        unsigned short val = f2bf(acc[ti][tj][r] * sc);
                        if (which == 0) Qb[((size_t)bh * 4096 + t) * 64 + d] = val;
                        else            Kb[((size_t)bh * 4096 + t) * 64 + d] = val;
                    }
                }
            }
        }
    } else {
        float* Out = (float*)outp;
        #pragma unroll
        for (int ti = 0; ti < 4; ++ti) {
            #pragma unroll
            for (int r = 0; r < 4; ++r) {
                int m = m0 + wr * 64 + ti * 16 + quad * 4 + r;
                #pragma unroll
                for (int tj = 0; tj < 4; ++tj) {
                    int n = n0 + wc * 64 + tj * 16 + l16;
                    Out[(size_t)m * 512 + n] = acc[ti][tj][r];
                }
            }
        }
    }
}

// ---------------- MFMA flash attention: uniform 33-slot pair-blocks -------------------
// Block = complementary pair (qbL=p, qbH=63-p) x bh: 512 blocks x 512 threads (8 waves).
// Wave role (qg=wave>>2, p2=(wave>>1)&1, w=wave&1) = exactly the r5/r8 per-wave core.
// Phase 1 (slots 0..p): tile s for BOTH q-groups (shared K/V staging). Transition:
// qbL written out (r8 epilogue), L-waves re-target to qbH. Phase 2 (slots 1..32-p):
// TWO tiles/slot -- H-waves odd tiles, L-waves even tiles of qbH (disjoint; diag always
// H-owned last slot). EVERY block = exactly 33 slots -> flat residency under ANY
// dispatch mapping; no cross-block coupling (r6/r7 lessons). LDS 64 KB (4 K/V tile
// buffers) x 2 blocks/CU = 16 waves/CU sustained (r8 decayed to ~8 -> 24% occ).
// Final: qbH 4-way combine (H+L, then w-halves) via end-of-kernel LDS reuse.
__global__ __launch_bounds__(512, 4) void attn_mfma(
    const unsigned short* __restrict__ Q,
    const unsigned short* __restrict__ K,
    const unsigned short* __restrict__ Vt,
    unsigned short* __restrict__ Y)
{
    __shared__ __align__(16) unsigned short smem[4][2][64][64];   // [buf][K/V][64][64]

    const int tid  = threadIdx.x;
    const int wave = tid >> 6;           // 0..7
    const int lane = tid & 63;
    const int l32  = lane & 31;
    const int hh   = lane >> 5;
    const int swz  = l32 & 7;
    const int qg   = wave >> 2;          // 0 = L-group, 1 = H-group
    const int p2   = (wave >> 1) & 1;    // row half
    const int w    = wave & 1;           // key half

    const int bid = blockIdx.x;
    const int bh  = bid & 15;
    const int pp  = bid >> 4;            // 0..31
    const int qbL = pp, qbH = 63 - pp;

    const unsigned short* Qp = Q  + (size_t)bh * (4096 * 64);
    const unsigned short* Kp = K  + (size_t)bh * (4096 * 64);
    const unsigned short* Vp = Vt + (size_t)bh * (64 * 4096);
    const int b = bh >> 3, h = bh & 7;

    short8 ones;
    #pragma unroll
    for (int i = 0; i < 8; ++i) ones[i] = (short)0x3F80;

    // Q frags for my phase-1 q-block (rows myqb*64 + 32*p2 + l32)
    const int myqb1 = qg ? qbH : qbL;
    short8 qf[4];
    #pragma unroll
    for (int k16 = 0; k16 < 4; ++k16)
        qf[k16] = *reinterpret_cast<const short8*>(
            &Qp[(size_t)(myqb1 * 64 + 32 * p2 + l32) * 64 + k16 * 16 + hh * 8]);

    floatx16 o0 = {0,0,0,0,0,0,0,0,0,0,0,0,0,0,0,0};
    floatx16 o1 = {0,0,0,0,0,0,0,0,0,0,0,0,0,0,0,0};
    floatx16 o4 = {0,0,0,0,0,0,0,0,0,0,0,0,0,0,0,0};

    // phase-1 staging: 512 threads, one 16KB tile: thread = K row rr + V row rr
    const int rr  = tid >> 3;            // 0..63
    const int cc  = tid & 7;
    const int c0  = cc * 8;
    const int scs = ((cc ^ (rr & 7)) << 3);

    {   // prologue: tile 0 -> buf 0
        uint4 k0v = *reinterpret_cast<const uint4*>(&Kp[(size_t)rr * 64 + c0]);
        uint4 v0v = *reinterpret_cast<const uint4*>(&Vp[(size_t)rr * 4096 + c0]);
        *reinterpret_cast<uint4*>(&smem[0][0][rr][scs]) = k0v;
        *reinterpret_cast<uint4*>(&smem[0][1][rr][scs]) = v0v;
    }

    // ---- phase 1: slots 0..pp ----
    uint4 rk, rv;
    for (int s = 0; s <= pp; ++s) {
        __syncthreads();
        const int cur = s & 1;
        if (s < pp) {
            rk = *reinterpret_cast<const uint4*>(&Kp[(size_t)((s + 1) * 64 + rr) * 64 + c0]);
            rv = *reinterpret_cast<const uint4*>(&Vp[(size_t)rr * 4096 + (s + 1) * 64 + c0]);
        }
        attn_tile(&smem[cur][0][0][0], &smem[cur][1][0][0], qf, ones,
                  (qg == 0) && (s == pp), l32, hh, swz, w, p2, o0, o1, o4);
        if (s < pp) {
            *reinterpret_cast<uint4*>(&smem[cur ^ 1][0][rr][scs]) = rk;
            *reinterpret_cast<uint4*>(&smem[cur ^ 1][1][rr][scs]) = rv;
        }
    }

    // ---- transition: qbL epilogue (L) overlapped with phase-2 first staging (H) ----
    __syncthreads();                                          // (A) bufs 0,1 free
    {
        float* ObM  = reinterpret_cast<float*>(&smem[0][0][0][0]);   // 16 KB
        float* WsfM = reinterpret_cast<float*>(&smem[1][0][0][0]);
        const int local = tid & 255;
        if (qg == 0) {
            const int lw = p2 * 2 + w;
            if (l32 == 0) {
                #pragma unroll
                for (int r = 0; r < 16; ++r) {
                    const int qloc = (r & 3) + 8 * (r >> 2) + 4 * hh;
                    WsfM[lw * 32 + qloc] = o4[r];
                }
            }
            #pragma unroll
            for (int r = 0; r < 16; ++r) {
                const int qloc = (r & 3) + 8 * (r >> 2) + 4 * hh;
                ObM[(lw * 32 + qloc) * 32 + l32] = w ? o0[r] : o1[r];
            }
        } else {
            // stage tiles pp+1 -> buf2, pp+2 -> buf3 (256 threads, r8 pattern)
            const int rr2 = local >> 3, cc2 = local & 7;
            const int c02 = cc2 * 8;
            const int sc2 = ((cc2 ^ (rr2 & 7)) << 3);
            const int tA = pp + 1;
            const int tB = (pp + 2 > 63) ? 63 : pp + 2;
            uint4 x0 = *reinterpret_cast<const uint4*>(&Kp[(size_t)(tA * 64 + rr2) * 64 + c02]);
            uint4 x1 = *reinterpret_cast<const uint4*>(&Kp[(size_t)(tA * 64 + rr2 + 32) * 64 + c02]);
            uint4 x2 = *reinterpret_cast<const uint4*>(&Vp[(size_t)rr2 * 4096 + tA * 64 + c02]);
            uint4 x3 = *reinterpret_cast<const uint4*>(&Vp[(size_t)(rr2 + 32) * 4096 + tA * 64 + c02]);
            *reinterpret_cast<uint4*>(&smem[2][0][rr2][sc2])      = x0;
            *reinterpret_cast<uint4*>(&smem[2][0][rr2 + 32][sc2]) = x1;
            *reinterpret_cast<uint4*>(&smem[2][1][rr2][sc2])      = x2;
            *reinterpret_cast<uint4*>(&smem[2][1][rr2 + 32][sc2]) = x3;
            x0 = *reinterpret_cast<const uint4*>(&Kp[(size_t)(tB * 64 + rr2) * 64 + c02]);
            x1 = *reinterpret_cast<const uint4*>(&Kp[(size_t)(tB * 64 + rr2 + 32) * 64 + c02]);
            x2 = *reinterpret_cast<const uint4*>(&Vp[(size_t)rr2 * 4096 + tB * 64 + c02]);
            x3 = *reinterpret_cast<const uint4*>(&Vp[(size_t)(rr2 + 32) * 4096 + tB * 64 + c02]);
            *reinterpret_cast<uint4*>(&smem[3][0][rr2][sc2])      = x0;
            *reinterpret_cast<uint4*>(&smem[3][0][rr2 + 32][sc2]) = x1;
            *reinterpret_cast<uint4*>(&smem[3][1][rr2][sc2])      = x2;
            *reinterpret_cast<uint4*>(&smem[3][1][rr2 + 32][sc2]) = x3;
        }
        __syncthreads();                                      // (B)
        if (qg == 0) {
            const int m0L = qbL * 64;
            #pragma unroll
            for (int gg = 0; gg < 4; ++gg) {
                float4 a4 = *reinterpret_cast<const float4*>(&WsfM[(p2 * 2 + 0) * 32 + 8 * gg + 4 * hh]);
                float4 b4 = *reinterpret_cast<const float4*>(&WsfM[(p2 * 2 + 1) * 32 + 8 * gg + 4 * hh]);
                const float ra[4] = {a4.x + b4.x, a4.y + b4.y, a4.z + b4.z, a4.w + b4.w};
                #pragma unroll
                for (int rsub = 0; rsub < 4; ++rsub) {
                    const int r = gg * 4 + rsub;
                    const int qloc = 8 * gg + 4 * hh + rsub;
                    const float cmb = (w ? o1[r] : o0[r])
                                    + ObM[((p2 * 2 + (1 - w)) * 32 + qloc) * 32 + l32];
                    const int t = m0L + 32 * p2 + qloc;
                    Y[((size_t)(b * 4096 + t)) * 512 + h * 64 + 32 * w + l32]
                        = f2bf(cmb / ra[rsub]);
                }
            }
            // re-target to qbH: fresh Q-frags + zero accumulators
            #pragma unroll
            for (int k16 = 0; k16 < 4; ++k16)
                qf[k16] = *reinterpret_cast<const short8*>(
                    &Qp[(size_t)(qbH * 64 + 32 * p2 + l32) * 64 + k16 * 16 + hh * 8]);
            #pragma unroll
            for (int r = 0; r < 16; ++r) { o0[r] = 0.f; o1[r] = 0.f; o4[r] = 0.f; }
        }
    }

    // ---- phase 2: slots 1..32-pp; H: tile pp+2s-1, L: tile pp+2s ----
    const int S2  = 32 - pp;
    const int rr2 = (tid & 255) >> 3;
    const int cc2 = (tid & 255) & 7;
    const int c02 = cc2 * 8;
    const int sc2 = ((cc2 ^ (rr2 & 7)) << 3);
    const int tsel = tid >> 8;           // 0: stages next tH, 1: next tL
    uint4 f0, f1, f2, f3;
    for (int s = 1; s <= S2; ++s) {
        __syncthreads();
        const int base = (s & 1) ? 2 : 0;
        if (s < S2) {
            int tn = pp + 2 * s + 1 + tsel;
            if (tn > 63) tn = 63;
            f0 = *reinterpret_cast<const uint4*>(&Kp[(size_t)(tn * 64 + rr2) * 64 + c02]);
            f1 = *reinterpret_cast<const uint4*>(&Kp[(size_t)(tn * 64 + rr2 + 32) * 64 + c02]);
            f2 = *reinterpret_cast<const uint4*>(&Vp[(size_t)rr2 * 4096 + tn * 64 + c02]);
            f3 = *reinterpret_cast<const uint4*>(&Vp[(size_t)(rr2 + 32) * 4096 + tn * 64 + c02]);
        }
        if (qg == 1) {
            attn_tile(&smem[base][0][0][0], &smem[base][1][0][0], qf, ones,
                      s == S2, l32, hh, swz, w, p2, o0, o1, o4);
        } else if (s < S2) {
            attn_tile(&smem[base + 1][0][0][0], &smem[base + 1][1][0][0], qf, ones,
                      false, l32, hh, swz, w, p2, o0, o1, o4);
        }
        if (s < S2) {
            const int tb = (base ^ 2) + tsel;
            *reinterpret_cast<uint4*>(&smem[tb][0][rr2][sc2])      = f0;
            *reinterpret_cast<uint4*>(&smem[tb][0][rr2 + 32][sc2]) = f1;
            *reinterpret_cast<uint4*>(&smem[tb][1][rr2][sc2])      = f2;
            *reinterpret_cast<uint4*>(&smem[tb][1][rr2 + 32][sc2]) = f3;
        }
    }

    // ---- final: qbH 4-way combine (H += L partials, then w-halves via r8 epilogue) --
    __syncthreads();                                          // (X) all LDS free
    float* Lo  = reinterpret_cast<float*>(&smem[0][0][0][0]); // 32 KB [4][32][64]
    float* Lrs = reinterpret_cast<float*>(&smem[2][0][0][0]); // [4][32]
    if (qg == 0) {
        const int lw = p2 * 2 + w;
        #pragma unroll
        for (int r = 0; r < 16; ++r) {
            const int qloc = (r & 3) + 8 * (r >> 2) + 4 * hh;
            Lo[(lw * 32 + qloc) * 64 + l32]      = o0[r];
            Lo[(lw * 32 + qloc) * 64 + 32 + l32] = o1[r];
        }
        if (l32 == 0) {
            #pragma unroll
            for (int r = 0; r < 16; ++r) {
                const int qloc = (r & 3) + 8 * (r >> 2) + 4 * hh;
                Lrs[lw * 32 + qloc] = o4[r];
            }
        }
    }
    __syncthreads();                                          // (Y)
    float* Ob2 = reinterpret_cast<float*>(&smem[3][0][0][0]); // 16 KB
    float* Ws2 = reinterpret_cast<float*>(&smem[2][1][0][0]);
    if (qg == 1) {
        const int lw = p2 * 2 + w;
        #pragma unroll
        for (int r = 0; r < 16; ++r) {
            const int qloc = (r & 3) + 8 * (r >> 2) + 4 * hh;
            o0[r] += Lo[(lw * 32 + qloc) * 64 + l32];
            o1[r] += Lo[(lw * 32 + qloc) * 64 + 32 + l32];
            o4[r] += Lrs[lw * 32 + qloc];
        }
        if (l32 == 0) {
            #pragma unroll
            for (int r = 0; r < 16; ++r) {
                const int qloc = (r & 3) + 8 * (r >> 2) + 4 * hh;
                Ws2[lw * 32 + qloc] = o4[r];
            }
        }
        #pragma unroll
        for (int r = 0; r < 16; ++r) {
            const int qloc = (r & 3) + 8 * (r >> 2) + 4 * hh;
            Ob2[(lw * 32 + qloc) * 32 + l32] = w ? o0[r] : o1[r];
        }
    }
    __syncthreads();                                          // (Z)
    if (qg == 1) {
        const int m0H = qbH * 64;
        #pragma unroll
        for (int gg = 0; gg < 4; ++gg) {
            float4 a4 = *reinterpret_cast<const float4*>(&Ws2[(p2 * 2 + 0) * 32 + 8 * gg + 4 * hh]);
            float4 b4 = *reinterpret_cast<const float4*>(&Ws2[(p2 * 2 + 1) * 32 + 8 * gg + 4 * hh]);
            const float ra[4] = {a4.x + b4.x, a4.y + b4.y, a4.z + b4.z, a4.w + b4.w};
            #pragma unroll
            for (int rsub = 0; rsub < 4; ++rsub) {
                const int r = gg * 4 + rsub;
                const int qloc = 8 * gg + 4 * hh + rsub;
                const float cmb = (w ? o1[r] : o0[r])
                                + Ob2[((p2 * 2 + (1 - w)) * 32 + qloc) * 32 + l32];
                const int t = m0H + 32 * p2 + qloc;
                Y[((size_t)(b * 4096 + t)) * 512 + h * 64 + 32 * w + l32]
                    = f2bf(cmb / ra[rsub]);
            }
        }
    }
}

extern "C" void kernel_launch(void* const* d_in, const int* in_sizes, int n_in,
                              void* d_out, int out_size, void* d_ws, size_t ws_size,
                              hipStream_t stream) {
    const float* x  = (const float*)d_in[0];
    const float* Wa = (const float*)d_in[1];
    const float* Wp = (const float*)d_in[2];
    float* out = (float*)d_out;
    unsigned short* ws = (unsigned short*)d_ws;

    unsigned short* Qb  = ws;
    unsigned short* Kb  = ws + 4194304;
    unsigned short* Vtb = ws + 8388608;
    unsigned short* Yb  = ws + 12582912;
    unsigned short* WaT = Yb;                      // W_attn^T during QKV only
    unsigned short* WpT = Qb;                      // W_proj^T after attn (Q dead)
    unsigned short* xb  = (unsigned short*)d_out;  // x bf16; overwritten by proj

    prep_a<<<dim3(2816), dim3(256), 0, stream>>>(x, xb, Wa, WaT);
    mm_bt<0><<<dim3(64, 12), dim3(256), 0, stream>>>(xb, WaT, (void*)ws);
    attn_mfma<<<dim3(512), dim3(512), 0, stream>>>(Qb, Kb, Vtb, Yb);
    transpose_wp<<<dim3(16, 16), dim3(256), 0, stream>>>(Wp, WpT);
    mm_bt<1><<<dim3(64, 4), dim3(256), 0, stream>>>(Yb, WpT, (void*)out);
}